// Round 1
// baseline (485.913 us; speedup 1.0000x reference)
//
#include <hip/hip_runtime.h>
#include <hip/hip_bf16.h>
#include <cstdint>
#include <cstddef>

#define NNODES 50000
#define NEDGES 800000
#define NIN    512
#define NHID   128
#define NCLS   64

// ---------------- CSR build ----------------

__global__ void deg_kernel(const int* __restrict__ dst, int* __restrict__ deg) {
    int e = blockIdx.x * blockDim.x + threadIdx.x;
    if (e < NEDGES) atomicAdd(&deg[dst[e]], 1);
}

__global__ void dinv_kernel(const int* __restrict__ deg, float* __restrict__ dinv) {
    int i = blockIdx.x * blockDim.x + threadIdx.x;
    if (i < NNODES) dinv[i] = rsqrtf((float)deg[i] + 1.0f);
}

// single-block exclusive scan of deg -> rowptr (N+1 entries)
__global__ void scan_kernel(const int* __restrict__ deg, int* __restrict__ rowptr) {
    __shared__ int part[1024];
    const int t = threadIdx.x;
    const int CH = (NNODES + 1023) / 1024;  // 49
    const int beg = t * CH;
    int sum = 0;
    for (int i = 0; i < CH; ++i) {
        int idx = beg + i;
        if (idx < NNODES) sum += deg[idx];
    }
    part[t] = sum;
    __syncthreads();
    int incl = sum;
    for (int off = 1; off < 1024; off <<= 1) {
        int other = (t >= off) ? part[t - off] : 0;
        __syncthreads();
        incl += other;
        part[t] = incl;
        __syncthreads();
    }
    int run = incl - sum;  // exclusive prefix of this chunk
    for (int i = 0; i < CH; ++i) {
        int idx = beg + i;
        if (idx < NNODES) { rowptr[idx] = run; run += deg[idx]; }
        else if (idx == NNODES) { rowptr[idx] = run; }
    }
}

__global__ void scatter_kernel(const int* __restrict__ src, const int* __restrict__ dst,
                               const int* __restrict__ rowptr, int* __restrict__ cursor,
                               const float* __restrict__ dinv, int2* __restrict__ csr) {
    int e = blockIdx.x * blockDim.x + threadIdx.x;
    if (e >= NEDGES) return;
    int d = dst[e];
    int s = src[e];
    int pos = rowptr[d] + atomicAdd(&cursor[d], 1);
    csr[pos] = make_int2(s, __float_as_int(dinv[s]));
}

// ---------------- f32 tiled GEMM: C[M x NOUT] = A[M x K] @ W[K x NOUT] ----------------
// block: 256 threads (tx 0..15, ty 0..15); tile: 32 rows x NOUT cols; K-chunk 32
template <int NOUT>
__global__ __launch_bounds__(256) void gemm_kernel(const float* __restrict__ A,
                                                   const float* __restrict__ W,
                                                   float* __restrict__ C, int M, int K) {
    constexpr int NG = NOUT / 64;  // float4 groups per thread (2 for 128, 1 for 64)
    __shared__ float sA[32][33];
    __shared__ float sW[32][NOUT];

    const int tx = threadIdx.x & 15;
    const int ty = threadIdx.x >> 4;
    const int rowBase = blockIdx.x * 32;

    float acc[2][NG][4];
#pragma unroll
    for (int r = 0; r < 2; ++r)
#pragma unroll
        for (int g = 0; g < NG; ++g)
#pragma unroll
            for (int c = 0; c < 4; ++c) acc[r][g][c] = 0.f;

    for (int k0 = 0; k0 < K; k0 += 32) {
        // A tile: 32x32, one float4 per thread
        {
            int i = threadIdx.x * 4;
            int r = i >> 5, c = i & 31;
            int gr = rowBase + r;
            float4 v = make_float4(0.f, 0.f, 0.f, 0.f);
            if (gr < M) v = *(const float4*)&A[(size_t)gr * K + k0 + c];
            sA[r][c] = v.x; sA[r][c + 1] = v.y; sA[r][c + 2] = v.z; sA[r][c + 3] = v.w;
        }
        // W tile: 32 x NOUT
        for (int i = threadIdx.x * 4; i < 32 * NOUT; i += 1024) {
            int r = i / NOUT, c = i % NOUT;
            *(float4*)&sW[r][c] = *(const float4*)&W[(size_t)(k0 + r) * NOUT + c];
        }
        __syncthreads();
#pragma unroll
        for (int kk = 0; kk < 32; ++kk) {
            float a0 = sA[ty * 2][kk];
            float a1 = sA[ty * 2 + 1][kk];
#pragma unroll
            for (int g = 0; g < NG; ++g) {
                float4 wv = *(const float4*)&sW[kk][tx * 4 + g * 64];
                acc[0][g][0] += a0 * wv.x; acc[0][g][1] += a0 * wv.y;
                acc[0][g][2] += a0 * wv.z; acc[0][g][3] += a0 * wv.w;
                acc[1][g][0] += a1 * wv.x; acc[1][g][1] += a1 * wv.y;
                acc[1][g][2] += a1 * wv.z; acc[1][g][3] += a1 * wv.w;
            }
        }
        __syncthreads();
    }
#pragma unroll
    for (int r = 0; r < 2; ++r) {
        int gr = rowBase + ty * 2 + r;
        if (gr < M) {
#pragma unroll
            for (int g = 0; g < NG; ++g) {
                float4 v = make_float4(acc[r][g][0], acc[r][g][1], acc[r][g][2], acc[r][g][3]);
                *(float4*)&C[(size_t)gr * NOUT + tx * 4 + g * 64] = v;
            }
        }
    }
}

// ---------------- aggregation layer 1: h = relu(agg(xw1) + b1), one wave per node ----------------
__global__ __launch_bounds__(256) void agg1_kernel(const float* __restrict__ xw,
                                                   const int* __restrict__ rowptr,
                                                   const int2* __restrict__ csr,
                                                   const float* __restrict__ dinv,
                                                   const float* __restrict__ b1,
                                                   float* __restrict__ h) {
    int wid = (blockIdx.x * blockDim.x + threadIdx.x) >> 6;
    int lane = threadIdx.x & 63;
    if (wid >= NNODES) return;
    int beg = rowptr[wid], end = rowptr[wid + 1];
    float a0 = 0.f, a1 = 0.f;
    for (int j = beg; j < end; ++j) {
        int2 e = csr[j];
        float wgt = __int_as_float(e.y);
        float2 v = *(const float2*)&xw[(size_t)e.x * NHID + lane * 2];
        a0 += wgt * v.x;
        a1 += wgt * v.y;
    }
    float di = dinv[wid];
    float sl = di * di;
    float2 xv = *(const float2*)&xw[(size_t)wid * NHID + lane * 2];
    float2 bv = *(const float2*)&b1[lane * 2];
    float r0 = di * a0 + sl * xv.x + bv.x;
    float r1 = di * a1 + sl * xv.y + bv.y;
    float2 o;
    o.x = fmaxf(r0, 0.f);
    o.y = fmaxf(r1, 0.f);
    *(float2*)&h[(size_t)wid * NHID + lane * 2] = o;
}

// ---------------- aggregation layer 2 + bias + log_softmax, one wave per node ----------------
__global__ __launch_bounds__(256) void agg2_kernel(const float* __restrict__ xw,
                                                   const int* __restrict__ rowptr,
                                                   const int2* __restrict__ csr,
                                                   const float* __restrict__ dinv,
                                                   const float* __restrict__ b2,
                                                   float* __restrict__ out) {
    int wid = (blockIdx.x * blockDim.x + threadIdx.x) >> 6;
    int lane = threadIdx.x & 63;
    if (wid >= NNODES) return;
    int beg = rowptr[wid], end = rowptr[wid + 1];
    float a = 0.f;
    for (int j = beg; j < end; ++j) {
        int2 e = csr[j];
        a += __int_as_float(e.y) * xw[(size_t)e.x * NCLS + lane];
    }
    float di = dinv[wid];
    float o = di * a + di * di * xw[(size_t)wid * NCLS + lane] + b2[lane];
    float m = o;
#pragma unroll
    for (int off = 32; off; off >>= 1) m = fmaxf(m, __shfl_xor(m, off, 64));
    float ex = __expf(o - m);
    float ssum = ex;
#pragma unroll
    for (int off = 32; off; off >>= 1) ssum += __shfl_xor(ssum, off, 64);
    out[(size_t)wid * NCLS + lane] = (o - m) - __logf(ssum);
}

// ---------------- launch ----------------

extern "C" void kernel_launch(void* const* d_in, const int* in_sizes, int n_in,
                              void* d_out, int out_size, void* d_ws, size_t ws_size,
                              hipStream_t stream) {
    const float* x  = (const float*)d_in[0];
    const int*   ei = (const int*)d_in[1];
    const int*   src = ei;
    const int*   dst = ei + NEDGES;
    const float* W1 = (const float*)d_in[2];
    const float* b1 = (const float*)d_in[3];
    const float* W2 = (const float*)d_in[4];
    const float* b2 = (const float*)d_in[5];
    float* out = (float*)d_out;

    char* w = (char*)d_ws;
    auto alloc = [&](size_t bytes) {
        char* p = w;
        w += (bytes + 255) & ~(size_t)255;
        return p;
    };
    int*   deg    = (int*)alloc(NNODES * 4);
    int*   cursor = (int*)alloc(NNODES * 4);
    int*   rowptr = (int*)alloc((NNODES + 1) * 4);
    int2*  csr    = (int2*)alloc((size_t)NEDGES * 8);
    float* dinv   = (float*)alloc(NNODES * 4);
    float* xw1    = (float*)alloc((size_t)NNODES * NHID * 4);
    float* h      = (float*)alloc((size_t)NNODES * NHID * 4);
    float* xw2    = (float*)alloc((size_t)NNODES * NCLS * 4);

    hipMemsetAsync(deg, 0, NNODES * 4, stream);
    hipMemsetAsync(cursor, 0, NNODES * 4, stream);

    deg_kernel<<<(NEDGES + 255) / 256, 256, 0, stream>>>(dst, deg);
    dinv_kernel<<<(NNODES + 255) / 256, 256, 0, stream>>>(deg, dinv);
    scan_kernel<<<1, 1024, 0, stream>>>(deg, rowptr);
    scatter_kernel<<<(NEDGES + 255) / 256, 256, 0, stream>>>(src, dst, rowptr, cursor, dinv, csr);

    // layer 1
    gemm_kernel<NHID><<<(NNODES + 31) / 32, 256, 0, stream>>>(x, W1, xw1, NNODES, NIN);
    agg1_kernel<<<(NNODES * 64 + 255) / 256, 256, 0, stream>>>(xw1, rowptr, csr, dinv, b1, h);

    // layer 2 (+ fused bias + log_softmax)
    gemm_kernel<NCLS><<<(NNODES + 31) / 32, 256, 0, stream>>>(h, W2, xw2, NNODES, NHID);
    agg2_kernel<<<(NNODES * 64 + 255) / 256, 256, 0, stream>>>(xw2, rowptr, csr, dinv, b2, out);
}

// Round 2
// 312.865 us; speedup vs baseline: 1.5531x; 1.5531x over previous
//
#include <hip/hip_runtime.h>
#include <hip/hip_bf16.h>
#include <cstdint>
#include <cstddef>

#define NNODES 50000
#define NEDGES 800000
#define NIN    512
#define NHID   128
#define NCLS   64

typedef __attribute__((ext_vector_type(8))) short bf16x8;
typedef __attribute__((ext_vector_type(4))) float f32x4;

static __device__ __forceinline__ ushort f2bf(float f) {
    uint32_t u = __float_as_uint(f);
    uint32_t r = (u + 0x7fffu + ((u >> 16) & 1u)) >> 16;  // RNE
    return (ushort)r;
}
static __device__ __forceinline__ float bf2f(ushort b) {
    return __uint_as_float(((uint32_t)b) << 16);
}

// ---------------- CSR build ----------------

__global__ void deg_kernel(const int* __restrict__ dst, int* __restrict__ deg) {
    int e = blockIdx.x * blockDim.x + threadIdx.x;
    if (e < NEDGES) atomicAdd(&deg[dst[e]], 1);
}

__global__ void dinv_kernel(const int* __restrict__ deg, float* __restrict__ dinv) {
    int i = blockIdx.x * blockDim.x + threadIdx.x;
    if (i < NNODES) dinv[i] = rsqrtf((float)deg[i] + 1.0f);
}

// single-block exclusive scan of deg -> rowptr (N+1 entries)
__global__ void scan_kernel(const int* __restrict__ deg, int* __restrict__ rowptr) {
    __shared__ int part[1024];
    const int t = threadIdx.x;
    const int CH = (NNODES + 1023) / 1024;  // 49
    const int beg = t * CH;
    int sum = 0;
    for (int i = 0; i < CH; ++i) {
        int idx = beg + i;
        if (idx < NNODES) sum += deg[idx];
    }
    part[t] = sum;
    __syncthreads();
    int incl = sum;
    for (int off = 1; off < 1024; off <<= 1) {
        int other = (t >= off) ? part[t - off] : 0;
        __syncthreads();
        incl += other;
        part[t] = incl;
        __syncthreads();
    }
    int run = incl - sum;
    for (int i = 0; i < CH; ++i) {
        int idx = beg + i;
        if (idx < NNODES) { rowptr[idx] = run; run += deg[idx]; }
        else if (idx == NNODES) { rowptr[idx] = run; }
    }
}

__global__ void scatter_kernel(const int* __restrict__ src, const int* __restrict__ dst,
                               const int* __restrict__ rowptr, int* __restrict__ cursor,
                               const float* __restrict__ dinv, int2* __restrict__ csr) {
    int e = blockIdx.x * blockDim.x + threadIdx.x;
    if (e >= NEDGES) return;
    int d = dst[e];
    int s = src[e];
    int pos = rowptr[d] + atomicAdd(&cursor[d], 1);
    csr[pos] = make_int2(s, __float_as_int(dinv[s]));
}

// ---------------- W pre-pack into MFMA B-fragment order (bf16) ----------------
// pack[((ks*CF + cf)*64 + lane)*8 + j] = bf16(W[(ks*32 + (lane>>4)*8 + j)*NOUT + cf*16 + (lane&15)])
template <int NOUT, int KS, int CF>
__global__ void pack_kernel(const float* __restrict__ W, ushort* __restrict__ pack) {
    int t = blockIdx.x * blockDim.x + threadIdx.x;
    if (t >= KS * CF * 64 * 8) return;
    int j = t & 7;
    int lane = (t >> 3) & 63;
    int cf = (t >> 9) % CF;
    int ks = t / (CF * 512);
    int k = ks * 32 + (lane >> 4) * 8 + j;
    int c = cf * 16 + (lane & 15);
    pack[t] = f2bf(W[(size_t)k * NOUT + c]);
}

// ---------------- GEMM1: xw1[50000x128](bf16) = x[50000x512](f32) @ packW1 ----------------
// one wave per 16 rows; A-fragments direct from global f32 + in-reg cvt; B from pack (L2-hot)
__global__ __launch_bounds__(256) void gemm1_kernel(const float* __restrict__ A,
                                                    const ushort* __restrict__ packB,
                                                    ushort* __restrict__ C) {
    int wid = (blockIdx.x * blockDim.x + threadIdx.x) >> 6;
    int lane = threadIdx.x & 63;
    int rowBase = wid * 16;
    if (rowBase >= NNODES) return;
    int rl = lane & 15;
    int kg = lane >> 4;
    const float* ap = A + (size_t)(rowBase + rl) * NIN + kg * 8;

    f32x4 acc[8];
#pragma unroll
    for (int cf = 0; cf < 8; ++cf) acc[cf] = (f32x4)(0.f);

    for (int ks = 0; ks < 16; ++ks) {
        float4 x0 = *(const float4*)(ap + ks * 32);
        float4 x1 = *(const float4*)(ap + ks * 32 + 4);
        bf16x8 af;
        af[0] = (short)f2bf(x0.x); af[1] = (short)f2bf(x0.y);
        af[2] = (short)f2bf(x0.z); af[3] = (short)f2bf(x0.w);
        af[4] = (short)f2bf(x1.x); af[5] = (short)f2bf(x1.y);
        af[6] = (short)f2bf(x1.z); af[7] = (short)f2bf(x1.w);
        const ushort* bp = packB + ((size_t)(ks * 8) * 64 + lane) * 8;
#pragma unroll
        for (int cf = 0; cf < 8; ++cf) {
            bf16x8 bf = *(const bf16x8*)(bp + (size_t)cf * 512);
            acc[cf] = __builtin_amdgcn_mfma_f32_16x16x32_bf16(af, bf, acc[cf], 0, 0, 0);
        }
    }
    // C/D: col = lane&15, row = (lane>>4)*4 + j   [m89-verified]
#pragma unroll
    for (int cf = 0; cf < 8; ++cf)
#pragma unroll
        for (int j = 0; j < 4; ++j)
            C[(size_t)(rowBase + kg * 4 + j) * NHID + cf * 16 + rl] = f2bf(acc[cf][j]);
}

// ---------------- GEMM2: xw2[50000x64](bf16) = h[50000x128](bf16) @ packW2 ----------------
__global__ __launch_bounds__(256) void gemm2_kernel(const ushort* __restrict__ A,
                                                    const ushort* __restrict__ packB,
                                                    ushort* __restrict__ C) {
    int wid = (blockIdx.x * blockDim.x + threadIdx.x) >> 6;
    int lane = threadIdx.x & 63;
    int rowBase = wid * 16;
    if (rowBase >= NNODES) return;
    int rl = lane & 15;
    int kg = lane >> 4;
    const ushort* ap = A + (size_t)(rowBase + rl) * NHID + kg * 8;

    f32x4 acc[4];
#pragma unroll
    for (int cf = 0; cf < 4; ++cf) acc[cf] = (f32x4)(0.f);

#pragma unroll
    for (int ks = 0; ks < 4; ++ks) {
        bf16x8 af = *(const bf16x8*)(ap + ks * 32);
        const ushort* bp = packB + ((size_t)(ks * 4) * 64 + lane) * 8;
#pragma unroll
        for (int cf = 0; cf < 4; ++cf) {
            bf16x8 bf = *(const bf16x8*)(bp + (size_t)cf * 512);
            acc[cf] = __builtin_amdgcn_mfma_f32_16x16x32_bf16(af, bf, acc[cf], 0, 0, 0);
        }
    }
#pragma unroll
    for (int cf = 0; cf < 4; ++cf)
#pragma unroll
        for (int j = 0; j < 4; ++j)
            C[(size_t)(rowBase + kg * 4 + j) * NCLS + cf * 16 + rl] = f2bf(acc[cf][j]);
}

// ---------------- agg1: h = relu(agg(xw1) + b1), one wave per node, bf16 in/out ----------------
__global__ __launch_bounds__(256) void agg1_kernel(const ushort* __restrict__ xw,
                                                   const int* __restrict__ rowptr,
                                                   const int2* __restrict__ csr,
                                                   const float* __restrict__ dinv,
                                                   const float* __restrict__ b1,
                                                   ushort* __restrict__ h) {
    int wid = (blockIdx.x * blockDim.x + threadIdx.x) >> 6;
    int lane = threadIdx.x & 63;
    if (wid >= NNODES) return;
    int beg = rowptr[wid], end = rowptr[wid + 1];
    float a0 = 0.f, a1 = 0.f;
    int j = beg;
    for (; j + 4 <= end; j += 4) {
        int2 e0 = csr[j], e1 = csr[j + 1], e2 = csr[j + 2], e3 = csr[j + 3];
        uint v0 = *(const uint*)&xw[(size_t)e0.x * NHID + lane * 2];
        uint v1 = *(const uint*)&xw[(size_t)e1.x * NHID + lane * 2];
        uint v2 = *(const uint*)&xw[(size_t)e2.x * NHID + lane * 2];
        uint v3 = *(const uint*)&xw[(size_t)e3.x * NHID + lane * 2];
        float w0 = __int_as_float(e0.y), w1 = __int_as_float(e1.y);
        float w2 = __int_as_float(e2.y), w3 = __int_as_float(e3.y);
        a0 += w0 * __uint_as_float(v0 << 16) + w1 * __uint_as_float(v1 << 16)
            + w2 * __uint_as_float(v2 << 16) + w3 * __uint_as_float(v3 << 16);
        a1 += w0 * __uint_as_float(v0 & 0xffff0000u) + w1 * __uint_as_float(v1 & 0xffff0000u)
            + w2 * __uint_as_float(v2 & 0xffff0000u) + w3 * __uint_as_float(v3 & 0xffff0000u);
    }
    for (; j < end; ++j) {
        int2 e = csr[j];
        float w = __int_as_float(e.y);
        uint v = *(const uint*)&xw[(size_t)e.x * NHID + lane * 2];
        a0 += w * __uint_as_float(v << 16);
        a1 += w * __uint_as_float(v & 0xffff0000u);
    }
    float di = dinv[wid];
    float sl = di * di;
    uint xv = *(const uint*)&xw[(size_t)wid * NHID + lane * 2];
    float2 bv = *(const float2*)&b1[lane * 2];
    float r0 = di * a0 + sl * __uint_as_float(xv << 16) + bv.x;
    float r1 = di * a1 + sl * __uint_as_float(xv & 0xffff0000u) + bv.y;
    uint o = (uint)f2bf(fmaxf(r0, 0.f)) | ((uint)f2bf(fmaxf(r1, 0.f)) << 16);
    *(uint*)&h[(size_t)wid * NHID + lane * 2] = o;
}

// ---------------- agg2 + bias + log_softmax, one wave per node, bf16 in, f32 out ----------------
__global__ __launch_bounds__(256) void agg2_kernel(const ushort* __restrict__ xw,
                                                   const int* __restrict__ rowptr,
                                                   const int2* __restrict__ csr,
                                                   const float* __restrict__ dinv,
                                                   const float* __restrict__ b2,
                                                   float* __restrict__ out) {
    int wid = (blockIdx.x * blockDim.x + threadIdx.x) >> 6;
    int lane = threadIdx.x & 63;
    if (wid >= NNODES) return;
    int beg = rowptr[wid], end = rowptr[wid + 1];
    float a = 0.f;
    int j = beg;
    for (; j + 4 <= end; j += 4) {
        int2 e0 = csr[j], e1 = csr[j + 1], e2 = csr[j + 2], e3 = csr[j + 3];
        float v0 = bf2f(xw[(size_t)e0.x * NCLS + lane]);
        float v1 = bf2f(xw[(size_t)e1.x * NCLS + lane]);
        float v2 = bf2f(xw[(size_t)e2.x * NCLS + lane]);
        float v3 = bf2f(xw[(size_t)e3.x * NCLS + lane]);
        a += __int_as_float(e0.y) * v0 + __int_as_float(e1.y) * v1
           + __int_as_float(e2.y) * v2 + __int_as_float(e3.y) * v3;
    }
    for (; j < end; ++j) {
        int2 e = csr[j];
        a += __int_as_float(e.y) * bf2f(xw[(size_t)e.x * NCLS + lane]);
    }
    float di = dinv[wid];
    float o = di * a + di * di * bf2f(xw[(size_t)wid * NCLS + lane]) + b2[lane];
    float m = o;
#pragma unroll
    for (int off = 32; off; off >>= 1) m = fmaxf(m, __shfl_xor(m, off, 64));
    float ex = __expf(o - m);
    float ssum = ex;
#pragma unroll
    for (int off = 32; off; off >>= 1) ssum += __shfl_xor(ssum, off, 64);
    out[(size_t)wid * NCLS + lane] = (o - m) - __logf(ssum);
}

// ---------------- launch ----------------

extern "C" void kernel_launch(void* const* d_in, const int* in_sizes, int n_in,
                              void* d_out, int out_size, void* d_ws, size_t ws_size,
                              hipStream_t stream) {
    const float* x  = (const float*)d_in[0];
    const int*   ei = (const int*)d_in[1];
    const int*   src = ei;
    const int*   dst = ei + NEDGES;
    const float* W1 = (const float*)d_in[2];
    const float* b1 = (const float*)d_in[3];
    const float* W2 = (const float*)d_in[4];
    const float* b2 = (const float*)d_in[5];
    float* out = (float*)d_out;

    char* w = (char*)d_ws;
    auto alloc = [&](size_t bytes) {
        char* p = w;
        w += (bytes + 255) & ~(size_t)255;
        return p;
    };
    int*    deg    = (int*)alloc(NNODES * 4);
    int*    cursor = (int*)alloc(NNODES * 4);
    int*    rowptr = (int*)alloc((NNODES + 1) * 4);
    int2*   csr    = (int2*)alloc((size_t)NEDGES * 8);
    float*  dinv   = (float*)alloc(NNODES * 4);
    ushort* pack1  = (ushort*)alloc((size_t)16 * 8 * 64 * 8 * 2);   // 128 KB
    ushort* pack2  = (ushort*)alloc((size_t)4 * 4 * 64 * 8 * 2);    // 16 KB
    ushort* xw1    = (ushort*)alloc((size_t)NNODES * NHID * 2);
    ushort* h      = (ushort*)alloc((size_t)NNODES * NHID * 2);
    ushort* xw2    = (ushort*)alloc((size_t)NNODES * NCLS * 2);

    hipMemsetAsync(deg, 0, NNODES * 4, stream);
    hipMemsetAsync(cursor, 0, NNODES * 4, stream);

    deg_kernel<<<(NEDGES + 255) / 256, 256, 0, stream>>>(dst, deg);
    dinv_kernel<<<(NNODES + 255) / 256, 256, 0, stream>>>(deg, dinv);
    scan_kernel<<<1, 1024, 0, stream>>>(deg, rowptr);
    scatter_kernel<<<(NEDGES + 255) / 256, 256, 0, stream>>>(src, dst, rowptr, cursor, dinv, csr);

    pack_kernel<NHID, 16, 8><<<(16 * 8 * 64 * 8 + 255) / 256, 256, 0, stream>>>(W1, pack1);
    pack_kernel<NCLS, 4, 4><<<(4 * 4 * 64 * 8 + 255) / 256, 256, 0, stream>>>(W2, pack2);

    // layer 1
    gemm1_kernel<<<(NNODES / 16 + 3) / 4, 256, 0, stream>>>(x, pack1, xw1);
    agg1_kernel<<<(NNODES * 64 + 255) / 256, 256, 0, stream>>>(xw1, rowptr, csr, dinv, b1, h);

    // layer 2 (+ fused bias + log_softmax)
    gemm2_kernel<<<(NNODES / 16 + 3) / 4, 256, 0, stream>>>(h, pack2, xw2);
    agg2_kernel<<<(NNODES * 64 + 255) / 256, 256, 0, stream>>>(xw2, rowptr, csr, dinv, b2, out);
}

// Round 3
// 227.380 us; speedup vs baseline: 2.1370x; 1.3760x over previous
//
#include <hip/hip_runtime.h>
#include <hip/hip_bf16.h>
#include <cstdint>
#include <cstddef>

#define NNODES 50000
#define NEDGES 800000
#define NIN    512
#define NHID   128
#define NCLS   64

#define SCAN_BLK 512
#define SCAN_NB ((NNODES + SCAN_BLK - 1) / SCAN_BLK)  // 98

typedef __attribute__((ext_vector_type(8))) short bf16x8;
typedef __attribute__((ext_vector_type(4))) float f32x4;

static __device__ __forceinline__ ushort f2bf(float f) {
    uint32_t u = __float_as_uint(f);
    uint32_t r = (u + 0x7fffu + ((u >> 16) & 1u)) >> 16;  // RNE
    return (ushort)r;
}
static __device__ __forceinline__ float bf2f(ushort b) {
    return __uint_as_float(((uint32_t)b) << 16);
}

// ---------------- CSR build ----------------

__global__ void deg_kernel(const int* __restrict__ dst, int* __restrict__ deg) {
    int e = blockIdx.x * blockDim.x + threadIdx.x;
    if (e < NEDGES) atomicAdd(&deg[dst[e]], 1);
}

// phase 1: per-block sums of deg; also compute dinv (fused)
__global__ __launch_bounds__(SCAN_BLK) void scan1_kernel(const int* __restrict__ deg,
                                                         int* __restrict__ blkSum,
                                                         float* __restrict__ dinv) {
    int i = blockIdx.x * SCAN_BLK + threadIdx.x;
    int d = (i < NNODES) ? deg[i] : 0;
    if (i < NNODES) dinv[i] = rsqrtf((float)d + 1.0f);
    int v = d;
#pragma unroll
    for (int off = 32; off; off >>= 1) v += __shfl_xor(v, off, 64);
    __shared__ int ws[SCAN_BLK / 64];
    int w = threadIdx.x >> 6;
    if ((threadIdx.x & 63) == 0) ws[w] = v;
    __syncthreads();
    if (threadIdx.x == 0) {
        int s = 0;
#pragma unroll
        for (int k = 0; k < SCAN_BLK / 64; ++k) s += ws[k];
        blkSum[blockIdx.x] = s;
    }
}

// phase 2: exclusive scan of the 98 block sums (single small block)
__global__ void scan2_kernel(int* __restrict__ blkSum, int* __restrict__ rowptr) {
    __shared__ int sh[128];
    int t = threadIdx.x;
    int v = (t < SCAN_NB) ? blkSum[t] : 0;
    sh[t] = v;
    __syncthreads();
    for (int off = 1; off < 128; off <<= 1) {
        int o = (t >= off) ? sh[t - off] : 0;
        __syncthreads();
        sh[t] += o;
        __syncthreads();
    }
    if (t < SCAN_NB) blkSum[t] = sh[t] - v;  // exclusive
    if (t == 0) rowptr[NNODES] = NEDGES;     // every edge has a dst
}

// phase 3: per-block exclusive scan + block offset -> rowptr
__global__ __launch_bounds__(SCAN_BLK) void scan3_kernel(const int* __restrict__ deg,
                                                         const int* __restrict__ blkOff,
                                                         int* __restrict__ rowptr) {
    int i = blockIdx.x * SCAN_BLK + threadIdx.x;
    int v = (i < NNODES) ? deg[i] : 0;
    int lane = threadIdx.x & 63;
    int w = threadIdx.x >> 6;
    int inc = v;
#pragma unroll
    for (int off = 1; off < 64; off <<= 1) {
        int o = __shfl_up(inc, off, 64);
        if (lane >= off) inc += o;
    }
    __shared__ int ws[SCAN_BLK / 64];
    if (lane == 63) ws[w] = inc;
    __syncthreads();
    int wpre = 0;
    for (int k = 0; k < w; ++k) wpre += ws[k];
    if (i < NNODES) rowptr[i] = inc - v + wpre + blkOff[blockIdx.x];
}

__global__ void scatter_kernel(const int* __restrict__ src, const int* __restrict__ dst,
                               const int* __restrict__ rowptr, int* __restrict__ cursor,
                               const float* __restrict__ dinv, int2* __restrict__ csr) {
    int e = blockIdx.x * blockDim.x + threadIdx.x;
    if (e >= NEDGES) return;
    int d = dst[e];
    int s = src[e];
    int pos = rowptr[d] + atomicAdd(&cursor[d], 1);
    csr[pos] = make_int2(s, __float_as_int(dinv[s]));
}

// ---------------- W pre-pack into MFMA B-fragment order (bf16) ----------------
template <int NOUT, int KS, int CF>
__global__ void pack_kernel(const float* __restrict__ W, ushort* __restrict__ pack) {
    int t = blockIdx.x * blockDim.x + threadIdx.x;
    if (t >= KS * CF * 64 * 8) return;
    int j = t & 7;
    int lane = (t >> 3) & 63;
    int cf = (t >> 9) % CF;
    int ks = t / (CF * 512);
    int k = ks * 32 + (lane >> 4) * 8 + j;
    int c = cf * 16 + (lane & 15);
    pack[t] = f2bf(W[(size_t)k * NOUT + c]);
}

// ---------------- GEMM1: xw1[50000x128](bf16) = x[50000x512](f32) @ packW1 ----------------
__global__ __launch_bounds__(256) void gemm1_kernel(const float* __restrict__ A,
                                                    const ushort* __restrict__ packB,
                                                    ushort* __restrict__ C) {
    int wid = (blockIdx.x * blockDim.x + threadIdx.x) >> 6;
    int lane = threadIdx.x & 63;
    int rowBase = wid * 16;
    if (rowBase >= NNODES) return;
    int rl = lane & 15;
    int kg = lane >> 4;
    const float* ap = A + (size_t)(rowBase + rl) * NIN + kg * 8;

    f32x4 acc[8];
#pragma unroll
    for (int cf = 0; cf < 8; ++cf) acc[cf] = (f32x4)(0.f);

    for (int ks = 0; ks < 16; ++ks) {
        float4 x0 = *(const float4*)(ap + ks * 32);
        float4 x1 = *(const float4*)(ap + ks * 32 + 4);
        bf16x8 af;
        af[0] = (short)f2bf(x0.x); af[1] = (short)f2bf(x0.y);
        af[2] = (short)f2bf(x0.z); af[3] = (short)f2bf(x0.w);
        af[4] = (short)f2bf(x1.x); af[5] = (short)f2bf(x1.y);
        af[6] = (short)f2bf(x1.z); af[7] = (short)f2bf(x1.w);
        const ushort* bp = packB + ((size_t)(ks * 8) * 64 + lane) * 8;
#pragma unroll
        for (int cf = 0; cf < 8; ++cf) {
            bf16x8 bf = *(const bf16x8*)(bp + (size_t)cf * 512);
            acc[cf] = __builtin_amdgcn_mfma_f32_16x16x32_bf16(af, bf, acc[cf], 0, 0, 0);
        }
    }
#pragma unroll
    for (int cf = 0; cf < 8; ++cf)
#pragma unroll
        for (int j = 0; j < 4; ++j)
            C[(size_t)(rowBase + kg * 4 + j) * NHID + cf * 16 + rl] = f2bf(acc[cf][j]);
}

// ---------------- GEMM2: xw2[50000x64](bf16) = h[50000x128](bf16) @ packW2 ----------------
__global__ __launch_bounds__(256) void gemm2_kernel(const ushort* __restrict__ A,
                                                    const ushort* __restrict__ packB,
                                                    ushort* __restrict__ C) {
    int wid = (blockIdx.x * blockDim.x + threadIdx.x) >> 6;
    int lane = threadIdx.x & 63;
    int rowBase = wid * 16;
    if (rowBase >= NNODES) return;
    int rl = lane & 15;
    int kg = lane >> 4;
    const ushort* ap = A + (size_t)(rowBase + rl) * NHID + kg * 8;

    f32x4 acc[4];
#pragma unroll
    for (int cf = 0; cf < 4; ++cf) acc[cf] = (f32x4)(0.f);

#pragma unroll
    for (int ks = 0; ks < 4; ++ks) {
        bf16x8 af = *(const bf16x8*)(ap + ks * 32);
        const ushort* bp = packB + ((size_t)(ks * 4) * 64 + lane) * 8;
#pragma unroll
        for (int cf = 0; cf < 4; ++cf) {
            bf16x8 bf = *(const bf16x8*)(bp + (size_t)cf * 512);
            acc[cf] = __builtin_amdgcn_mfma_f32_16x16x32_bf16(af, bf, acc[cf], 0, 0, 0);
        }
    }
#pragma unroll
    for (int cf = 0; cf < 4; ++cf)
#pragma unroll
        for (int j = 0; j < 4; ++j)
            C[(size_t)(rowBase + kg * 4 + j) * NCLS + cf * 16 + rl] = f2bf(acc[cf][j]);
}

// ---------------- agg1: h = relu(agg(xw1) + b1), one wave per node, bf16 in/out ----------------
__global__ __launch_bounds__(256) void agg1_kernel(const ushort* __restrict__ xw,
                                                   const int* __restrict__ rowptr,
                                                   const int2* __restrict__ csr,
                                                   const float* __restrict__ dinv,
                                                   const float* __restrict__ b1,
                                                   ushort* __restrict__ h) {
    int wid = (blockIdx.x * blockDim.x + threadIdx.x) >> 6;
    int lane = threadIdx.x & 63;
    if (wid >= NNODES) return;
    int beg = rowptr[wid], end = rowptr[wid + 1];
    float a0 = 0.f, a1 = 0.f;
    int j = beg;
    for (; j + 4 <= end; j += 4) {
        int2 e0 = csr[j], e1 = csr[j + 1], e2 = csr[j + 2], e3 = csr[j + 3];
        uint v0 = *(const uint*)&xw[(size_t)e0.x * NHID + lane * 2];
        uint v1 = *(const uint*)&xw[(size_t)e1.x * NHID + lane * 2];
        uint v2 = *(const uint*)&xw[(size_t)e2.x * NHID + lane * 2];
        uint v3 = *(const uint*)&xw[(size_t)e3.x * NHID + lane * 2];
        float w0 = __int_as_float(e0.y), w1 = __int_as_float(e1.y);
        float w2 = __int_as_float(e2.y), w3 = __int_as_float(e3.y);
        a0 += w0 * __uint_as_float(v0 << 16) + w1 * __uint_as_float(v1 << 16)
            + w2 * __uint_as_float(v2 << 16) + w3 * __uint_as_float(v3 << 16);
        a1 += w0 * __uint_as_float(v0 & 0xffff0000u) + w1 * __uint_as_float(v1 & 0xffff0000u)
            + w2 * __uint_as_float(v2 & 0xffff0000u) + w3 * __uint_as_float(v3 & 0xffff0000u);
    }
    for (; j < end; ++j) {
        int2 e = csr[j];
        float w = __int_as_float(e.y);
        uint v = *(const uint*)&xw[(size_t)e.x * NHID + lane * 2];
        a0 += w * __uint_as_float(v << 16);
        a1 += w * __uint_as_float(v & 0xffff0000u);
    }
    float di = dinv[wid];
    float sl = di * di;
    uint xv = *(const uint*)&xw[(size_t)wid * NHID + lane * 2];
    float2 bv = *(const float2*)&b1[lane * 2];
    float r0 = di * a0 + sl * __uint_as_float(xv << 16) + bv.x;
    float r1 = di * a1 + sl * __uint_as_float(xv & 0xffff0000u) + bv.y;
    uint o = (uint)f2bf(fmaxf(r0, 0.f)) | ((uint)f2bf(fmaxf(r1, 0.f)) << 16);
    *(uint*)&h[(size_t)wid * NHID + lane * 2] = o;
}

// ---------------- agg2 + bias + log_softmax, one wave per node, bf16 in, f32 out ----------------
__global__ __launch_bounds__(256) void agg2_kernel(const ushort* __restrict__ xw,
                                                   const int* __restrict__ rowptr,
                                                   const int2* __restrict__ csr,
                                                   const float* __restrict__ dinv,
                                                   const float* __restrict__ b2,
                                                   float* __restrict__ out) {
    int wid = (blockIdx.x * blockDim.x + threadIdx.x) >> 6;
    int lane = threadIdx.x & 63;
    if (wid >= NNODES) return;
    int beg = rowptr[wid], end = rowptr[wid + 1];
    float a = 0.f;
    int j = beg;
    for (; j + 4 <= end; j += 4) {
        int2 e0 = csr[j], e1 = csr[j + 1], e2 = csr[j + 2], e3 = csr[j + 3];
        float v0 = bf2f(xw[(size_t)e0.x * NCLS + lane]);
        float v1 = bf2f(xw[(size_t)e1.x * NCLS + lane]);
        float v2 = bf2f(xw[(size_t)e2.x * NCLS + lane]);
        float v3 = bf2f(xw[(size_t)e3.x * NCLS + lane]);
        a += __int_as_float(e0.y) * v0 + __int_as_float(e1.y) * v1
           + __int_as_float(e2.y) * v2 + __int_as_float(e3.y) * v3;
    }
    for (; j < end; ++j) {
        int2 e = csr[j];
        a += __int_as_float(e.y) * bf2f(xw[(size_t)e.x * NCLS + lane]);
    }
    float di = dinv[wid];
    float o = di * a + di * di * bf2f(xw[(size_t)wid * NCLS + lane]) + b2[lane];
    float m = o;
#pragma unroll
    for (int off = 32; off; off >>= 1) m = fmaxf(m, __shfl_xor(m, off, 64));
    float ex = __expf(o - m);
    float ssum = ex;
#pragma unroll
    for (int off = 32; off; off >>= 1) ssum += __shfl_xor(ssum, off, 64);
    out[(size_t)wid * NCLS + lane] = (o - m) - __logf(ssum);
}

// ---------------- launch ----------------

extern "C" void kernel_launch(void* const* d_in, const int* in_sizes, int n_in,
                              void* d_out, int out_size, void* d_ws, size_t ws_size,
                              hipStream_t stream) {
    const float* x  = (const float*)d_in[0];
    const int*   ei = (const int*)d_in[1];
    const int*   src = ei;
    const int*   dst = ei + NEDGES;
    const float* W1 = (const float*)d_in[2];
    const float* b1 = (const float*)d_in[3];
    const float* W2 = (const float*)d_in[4];
    const float* b2 = (const float*)d_in[5];
    float* out = (float*)d_out;

    char* w = (char*)d_ws;
    auto alloc = [&](size_t bytes) {
        char* p = w;
        w += (bytes + 255) & ~(size_t)255;
        return p;
    };
    int*    deg    = (int*)alloc((size_t)2 * NNODES * 4);  // deg + cursor (one memset)
    int*    cursor = deg + NNODES;
    int*    rowptr = (int*)alloc((NNODES + 1) * 4);
    int*    blkSum = (int*)alloc(SCAN_NB * 4);
    int2*   csr    = (int2*)alloc((size_t)NEDGES * 8);
    float*  dinv   = (float*)alloc(NNODES * 4);
    ushort* pack1  = (ushort*)alloc((size_t)16 * 8 * 64 * 8 * 2);
    ushort* pack2  = (ushort*)alloc((size_t)4 * 4 * 64 * 8 * 2);
    ushort* xw1    = (ushort*)alloc((size_t)NNODES * NHID * 2);
    ushort* h      = (ushort*)alloc((size_t)NNODES * NHID * 2);
    ushort* xw2    = (ushort*)alloc((size_t)NNODES * NCLS * 2);

    hipMemsetAsync(deg, 0, (size_t)2 * NNODES * 4, stream);

    deg_kernel<<<(NEDGES + 255) / 256, 256, 0, stream>>>(dst, deg);
    scan1_kernel<<<SCAN_NB, SCAN_BLK, 0, stream>>>(deg, blkSum, dinv);
    scan2_kernel<<<1, 128, 0, stream>>>(blkSum, rowptr);
    scan3_kernel<<<SCAN_NB, SCAN_BLK, 0, stream>>>(deg, blkSum, rowptr);
    scatter_kernel<<<(NEDGES + 255) / 256, 256, 0, stream>>>(src, dst, rowptr, cursor, dinv, csr);

    pack_kernel<NHID, 16, 8><<<(16 * 8 * 64 * 8 + 255) / 256, 256, 0, stream>>>(W1, pack1);
    pack_kernel<NCLS, 4, 4><<<(4 * 4 * 64 * 8 + 255) / 256, 256, 0, stream>>>(W2, pack2);

    // layer 1
    gemm1_kernel<<<(NNODES / 16 + 3) / 4, 256, 0, stream>>>(x, pack1, xw1);
    agg1_kernel<<<(NNODES * 64 + 255) / 256, 256, 0, stream>>>(xw1, rowptr, csr, dinv, b1, h);

    // layer 2 (+ fused bias + log_softmax)
    gemm2_kernel<<<(NNODES / 16 + 3) / 4, 256, 0, stream>>>(h, pack2, xw2);
    agg2_kernel<<<(NNODES * 64 + 255) / 256, 256, 0, stream>>>(xw2, rowptr, csr, dinv, b2, out);
}

// Round 5
// 217.829 us; speedup vs baseline: 2.2307x; 1.0438x over previous
//
#include <hip/hip_runtime.h>
#include <hip/hip_bf16.h>
#include <cstdint>
#include <cstddef>

#define NNODES 50000
#define NEDGES 800000
#define NIN    512
#define NHID   128
#define NCLS   64

#define SCAN_BLK 512
#define SCAN_NB ((NNODES + SCAN_BLK - 1) / SCAN_BLK)  // 98

typedef __attribute__((ext_vector_type(8))) short bf16x8;
typedef __attribute__((ext_vector_type(4))) float f32x4;

static __device__ __forceinline__ ushort f2bf(float f) {
    uint32_t u = __float_as_uint(f);
    uint32_t r = (u + 0x7fffu + ((u >> 16) & 1u)) >> 16;  // RNE
    return (ushort)r;
}
static __device__ __forceinline__ float bf2f(ushort b) {
    return __uint_as_float(((uint32_t)b) << 16);
}

// ---------------- CSR build ----------------

__global__ void deg_kernel(const int* __restrict__ dst, int* __restrict__ deg) {
    int e = blockIdx.x * blockDim.x + threadIdx.x;
    if (e < NEDGES) atomicAdd(&deg[dst[e]], 1);
}

// phase 1: per-block sums of deg; also compute dinv (fused)
__global__ __launch_bounds__(SCAN_BLK) void scan1_kernel(const int* __restrict__ deg,
                                                         int* __restrict__ blkSum,
                                                         float* __restrict__ dinv) {
    int i = blockIdx.x * SCAN_BLK + threadIdx.x;
    int d = (i < NNODES) ? deg[i] : 0;
    if (i < NNODES) dinv[i] = rsqrtf((float)d + 1.0f);
    int v = d;
#pragma unroll
    for (int off = 32; off; off >>= 1) v += __shfl_xor(v, off, 64);
    __shared__ int ws[SCAN_BLK / 64];
    int w = threadIdx.x >> 6;
    if ((threadIdx.x & 63) == 0) ws[w] = v;
    __syncthreads();
    if (threadIdx.x == 0) {
        int s = 0;
#pragma unroll
        for (int k = 0; k < SCAN_BLK / 64; ++k) s += ws[k];
        blkSum[blockIdx.x] = s;
    }
}

// phase 2: exclusive scan of the 98 block sums (single small block)
__global__ void scan2_kernel(int* __restrict__ blkSum, int* __restrict__ rowptr) {
    __shared__ int sh[128];
    int t = threadIdx.x;
    int v = (t < SCAN_NB) ? blkSum[t] : 0;
    sh[t] = v;
    __syncthreads();
    for (int off = 1; off < 128; off <<= 1) {
        int o = (t >= off) ? sh[t - off] : 0;
        __syncthreads();
        sh[t] += o;
        __syncthreads();
    }
    if (t < SCAN_NB) blkSum[t] = sh[t] - v;  // exclusive
    if (t == 0) rowptr[NNODES] = NEDGES;     // every edge has a dst
}

// phase 3: per-block exclusive scan + block offset -> rowptr
__global__ __launch_bounds__(SCAN_BLK) void scan3_kernel(const int* __restrict__ deg,
                                                         const int* __restrict__ blkOff,
                                                         int* __restrict__ rowptr) {
    int i = blockIdx.x * SCAN_BLK + threadIdx.x;
    int v = (i < NNODES) ? deg[i] : 0;
    int lane = threadIdx.x & 63;
    int w = threadIdx.x >> 6;
    int inc = v;
#pragma unroll
    for (int off = 1; off < 64; off <<= 1) {
        int o = __shfl_up(inc, off, 64);
        if (lane >= off) inc += o;
    }
    __shared__ int ws[SCAN_BLK / 64];
    if (lane == 63) ws[w] = inc;
    __syncthreads();
    int wpre = 0;
    for (int k = 0; k < w; ++k) wpre += ws[k];
    if (i < NNODES) rowptr[i] = inc - v + wpre + blkOff[blockIdx.x];
}

__global__ void scatter_kernel(const int* __restrict__ src, const int* __restrict__ dst,
                               const int* __restrict__ rowptr, int* __restrict__ cursor,
                               const float* __restrict__ dinv, int2* __restrict__ csr) {
    int e = blockIdx.x * blockDim.x + threadIdx.x;
    if (e >= NEDGES) return;
    int d = dst[e];
    int s = src[e];
    int pos = rowptr[d] + atomicAdd(&cursor[d], 1);
    csr[pos] = make_int2(s, __float_as_int(dinv[s]));
}

// ---------------- W pre-pack into MFMA B-fragment order (bf16) ----------------
template <int NOUT, int KS, int CF>
__global__ void pack_kernel(const float* __restrict__ W, ushort* __restrict__ pack) {
    int t = blockIdx.x * blockDim.x + threadIdx.x;
    if (t >= KS * CF * 64 * 8) return;
    int j = t & 7;
    int lane = (t >> 3) & 63;
    int cf = (t >> 9) % CF;
    int ks = t / (CF * 512);
    int k = ks * 32 + (lane >> 4) * 8 + j;
    int c = cf * 16 + (lane & 15);
    pack[t] = f2bf(W[(size_t)k * NOUT + c]);
}

// ---------------- GEMM1: xw1[50000x128](bf16) = x[50000x512](f32) @ packW1 ----------------
// depth-3 A prefetch into 4-slot buffer (prefetch slot (ks+3)&3 != consume slot ks&3),
// depth-1 B double-buffer (L2-hot pack)
__global__ __launch_bounds__(256) void gemm1_kernel(const float* __restrict__ A,
                                                    const ushort* __restrict__ packB,
                                                    ushort* __restrict__ C) {
    int wid = (blockIdx.x * blockDim.x + threadIdx.x) >> 6;
    int lane = threadIdx.x & 63;
    int rowBase = wid * 16;
    if (rowBase >= NNODES) return;
    int rl = lane & 15;
    int kg = lane >> 4;
    const float* ap = A + (size_t)(rowBase + rl) * NIN + kg * 8;
    const ushort* bp = packB + (size_t)lane * 8;

    f32x4 acc[8];
#pragma unroll
    for (int cf = 0; cf < 8; ++cf) acc[cf] = (f32x4)(0.f);

    float4 a0[4], a1[4];
    bf16x8 bb[2][8];
#pragma unroll
    for (int p = 0; p < 3; ++p) {
        a0[p] = *(const float4*)(ap + p * 32);
        a1[p] = *(const float4*)(ap + p * 32 + 4);
    }
#pragma unroll
    for (int cf = 0; cf < 8; ++cf) bb[0][cf] = *(const bf16x8*)(bp + cf * 512);

#pragma unroll
    for (int ks = 0; ks < 16; ++ks) {
        // prefetch A for ks+3 into slot (ks+3)&3 — disjoint from consume slot ks&3
        if (ks + 3 < 16) {
            a0[(ks + 3) & 3] = *(const float4*)(ap + (ks + 3) * 32);
            a1[(ks + 3) & 3] = *(const float4*)(ap + (ks + 3) * 32 + 4);
        }
        // prefetch B for ks+1 (slot (ks+1)&1 != ks&1)
        if (ks + 1 < 16) {
#pragma unroll
            for (int cf = 0; cf < 8; ++cf)
                bb[(ks + 1) & 1][cf] = *(const bf16x8*)(bp + (ks + 1) * 4096 + cf * 512);
        }
        float4 x0 = a0[ks & 3], x1 = a1[ks & 3];
        bf16x8 af;
        af[0] = (short)f2bf(x0.x); af[1] = (short)f2bf(x0.y);
        af[2] = (short)f2bf(x0.z); af[3] = (short)f2bf(x0.w);
        af[4] = (short)f2bf(x1.x); af[5] = (short)f2bf(x1.y);
        af[6] = (short)f2bf(x1.z); af[7] = (short)f2bf(x1.w);
#pragma unroll
        for (int cf = 0; cf < 8; ++cf)
            acc[cf] = __builtin_amdgcn_mfma_f32_16x16x32_bf16(af, bb[ks & 1][cf], acc[cf], 0, 0, 0);
    }
    // C/D: col = lane&15, row = (lane>>4)*4 + j   [m89-verified]
#pragma unroll
    for (int cf = 0; cf < 8; ++cf)
#pragma unroll
        for (int j = 0; j < 4; ++j)
            C[(size_t)(rowBase + kg * 4 + j) * NHID + cf * 16 + rl] = f2bf(acc[cf][j]);
}

// ---------------- GEMM2: xw2[50000x64](bf16) = h[50000x128](bf16) @ packW2 ----------------
__global__ __launch_bounds__(256) void gemm2_kernel(const ushort* __restrict__ A,
                                                    const ushort* __restrict__ packB,
                                                    ushort* __restrict__ C) {
    int wid = (blockIdx.x * blockDim.x + threadIdx.x) >> 6;
    int lane = threadIdx.x & 63;
    int rowBase = wid * 16;
    if (rowBase >= NNODES) return;
    int rl = lane & 15;
    int kg = lane >> 4;
    const ushort* ap = A + (size_t)(rowBase + rl) * NHID + kg * 8;

    f32x4 acc[4];
#pragma unroll
    for (int cf = 0; cf < 4; ++cf) acc[cf] = (f32x4)(0.f);

#pragma unroll
    for (int ks = 0; ks < 4; ++ks) {
        bf16x8 af = *(const bf16x8*)(ap + ks * 32);
        const ushort* bp = packB + ((size_t)(ks * 4) * 64 + lane) * 8;
#pragma unroll
        for (int cf = 0; cf < 4; ++cf) {
            bf16x8 bf = *(const bf16x8*)(bp + (size_t)cf * 512);
            acc[cf] = __builtin_amdgcn_mfma_f32_16x16x32_bf16(af, bf, acc[cf], 0, 0, 0);
        }
    }
#pragma unroll
    for (int cf = 0; cf < 4; ++cf)
#pragma unroll
        for (int j = 0; j < 4; ++j)
            C[(size_t)(rowBase + kg * 4 + j) * NCLS + cf * 16 + rl] = f2bf(acc[cf][j]);
}

// ---------------- agg1: h = relu(agg(xw1) + b1), one wave per node, bf16 in/out ----------------
__global__ __launch_bounds__(256) void agg1_kernel(const ushort* __restrict__ xw,
                                                   const int* __restrict__ rowptr,
                                                   const int2* __restrict__ csr,
                                                   const float* __restrict__ dinv,
                                                   const float* __restrict__ b1,
                                                   ushort* __restrict__ h) {
    int wid = (blockIdx.x * blockDim.x + threadIdx.x) >> 6;
    int lane = threadIdx.x & 63;
    if (wid >= NNODES) return;
    int beg = rowptr[wid], end = rowptr[wid + 1];
    float a0 = 0.f, a1 = 0.f;
    int j = beg;
    for (; j + 8 <= end; j += 8) {
        int2 e[8];
#pragma unroll
        for (int q = 0; q < 8; ++q) e[q] = csr[j + q];
        uint v[8];
#pragma unroll
        for (int q = 0; q < 8; ++q) v[q] = *(const uint*)&xw[(size_t)e[q].x * NHID + lane * 2];
#pragma unroll
        for (int q = 0; q < 8; ++q) {
            float wq = __int_as_float(e[q].y);
            a0 += wq * __uint_as_float(v[q] << 16);
            a1 += wq * __uint_as_float(v[q] & 0xffff0000u);
        }
    }
    for (; j < end; ++j) {
        int2 e = csr[j];
        float w = __int_as_float(e.y);
        uint v = *(const uint*)&xw[(size_t)e.x * NHID + lane * 2];
        a0 += w * __uint_as_float(v << 16);
        a1 += w * __uint_as_float(v & 0xffff0000u);
    }
    float di = dinv[wid];
    float sl = di * di;
    uint xv = *(const uint*)&xw[(size_t)wid * NHID + lane * 2];
    float2 bv = *(const float2*)&b1[lane * 2];
    float r0 = di * a0 + sl * __uint_as_float(xv << 16) + bv.x;
    float r1 = di * a1 + sl * __uint_as_float(xv & 0xffff0000u) + bv.y;
    uint o = (uint)f2bf(fmaxf(r0, 0.f)) | ((uint)f2bf(fmaxf(r1, 0.f)) << 16);
    *(uint*)&h[(size_t)wid * NHID + lane * 2] = o;
}

// ---------------- agg2 + bias + log_softmax, one wave per node, bf16 in, f32 out ----------------
__global__ __launch_bounds__(256) void agg2_kernel(const ushort* __restrict__ xw,
                                                   const int* __restrict__ rowptr,
                                                   const int2* __restrict__ csr,
                                                   const float* __restrict__ dinv,
                                                   const float* __restrict__ b2,
                                                   float* __restrict__ out) {
    int wid = (blockIdx.x * blockDim.x + threadIdx.x) >> 6;
    int lane = threadIdx.x & 63;
    if (wid >= NNODES) return;
    int beg = rowptr[wid], end = rowptr[wid + 1];
    float a = 0.f;
    int j = beg;
    for (; j + 8 <= end; j += 8) {
        int2 e[8];
#pragma unroll
        for (int q = 0; q < 8; ++q) e[q] = csr[j + q];
        float v[8];
#pragma unroll
        for (int q = 0; q < 8; ++q) v[q] = bf2f(xw[(size_t)e[q].x * NCLS + lane]);
#pragma unroll
        for (int q = 0; q < 8; ++q) a += __int_as_float(e[q].y) * v[q];
    }
    for (; j < end; ++j) {
        int2 e = csr[j];
        a += __int_as_float(e.y) * bf2f(xw[(size_t)e.x * NCLS + lane]);
    }
    float di = dinv[wid];
    float o = di * a + di * di * bf2f(xw[(size_t)wid * NCLS + lane]) + b2[lane];
    float m = o;
#pragma unroll
    for (int off = 32; off; off >>= 1) m = fmaxf(m, __shfl_xor(m, off, 64));
    float ex = __expf(o - m);
    float ssum = ex;
#pragma unroll
    for (int off = 32; off; off >>= 1) ssum += __shfl_xor(ssum, off, 64);
    out[(size_t)wid * NCLS + lane] = (o - m) - __logf(ssum);
}

// ---------------- launch ----------------

extern "C" void kernel_launch(void* const* d_in, const int* in_sizes, int n_in,
                              void* d_out, int out_size, void* d_ws, size_t ws_size,
                              hipStream_t stream) {
    const float* x  = (const float*)d_in[0];
    const int*   ei = (const int*)d_in[1];
    const int*   src = ei;
    const int*   dst = ei + NEDGES;
    const float* W1 = (const float*)d_in[2];
    const float* b1 = (const float*)d_in[3];
    const float* W2 = (const float*)d_in[4];
    const float* b2 = (const float*)d_in[5];
    float* out = (float*)d_out;

    char* w = (char*)d_ws;
    auto alloc = [&](size_t bytes) {
        char* p = w;
        w += (bytes + 255) & ~(size_t)255;
        return p;
    };
    int*    deg    = (int*)alloc((size_t)2 * NNODES * 4);  // deg + cursor (one memset)
    int*    cursor = deg + NNODES;
    int*    rowptr = (int*)alloc((NNODES + 1) * 4);
    int*    blkSum = (int*)alloc(SCAN_NB * 4);
    int2*   csr    = (int2*)alloc((size_t)NEDGES * 8);
    float*  dinv   = (float*)alloc(NNODES * 4);
    ushort* pack1  = (ushort*)alloc((size_t)16 * 8 * 64 * 8 * 2);
    ushort* pack2  = (ushort*)alloc((size_t)4 * 4 * 64 * 8 * 2);
    ushort* xw1    = (ushort*)alloc((size_t)NNODES * NHID * 2);
    ushort* h      = (ushort*)alloc((size_t)NNODES * NHID * 2);
    ushort* xw2    = (ushort*)alloc((size_t)NNODES * NCLS * 2);

    hipMemsetAsync(deg, 0, (size_t)2 * NNODES * 4, stream);

    deg_kernel<<<(NEDGES + 255) / 256, 256, 0, stream>>>(dst, deg);
    scan1_kernel<<<SCAN_NB, SCAN_BLK, 0, stream>>>(deg, blkSum, dinv);
    scan2_kernel<<<1, 128, 0, stream>>>(blkSum, rowptr);
    scan3_kernel<<<SCAN_NB, SCAN_BLK, 0, stream>>>(deg, blkSum, rowptr);
    scatter_kernel<<<(NEDGES + 255) / 256, 256, 0, stream>>>(src, dst, rowptr, cursor, dinv, csr);

    pack_kernel<NHID, 16, 8><<<(16 * 8 * 64 * 8 + 255) / 256, 256, 0, stream>>>(W1, pack1);
    pack_kernel<NCLS, 4, 4><<<(4 * 4 * 64 * 8 + 255) / 256, 256, 0, stream>>>(W2, pack2);

    // layer 1
    gemm1_kernel<<<(NNODES / 16 + 3) / 4, 256, 0, stream>>>(x, pack1, xw1);
    agg1_kernel<<<(NNODES * 64 + 255) / 256, 256, 0, stream>>>(xw1, rowptr, csr, dinv, b1, h);

    // layer 2 (+ fused bias + log_softmax)
    gemm2_kernel<<<(NNODES / 16 + 3) / 4, 256, 0, stream>>>(h, pack2, xw2);
    agg2_kernel<<<(NNODES * 64 + 255) / 256, 256, 0, stream>>>(xw2, rowptr, csr, dinv, b2, out);
}

// Round 6
// 212.667 us; speedup vs baseline: 2.2849x; 1.0243x over previous
//
#include <hip/hip_runtime.h>
#include <hip/hip_bf16.h>
#include <cstdint>
#include <cstddef>

#define NNODES 50000
#define NEDGES 800000
#define NIN    512
#define NHID   128
#define NCLS   64

#define SCAN_BLK 512
#define SCAN_NB ((NNODES + SCAN_BLK - 1) / SCAN_BLK)  // 98

typedef __attribute__((ext_vector_type(8))) short bf16x8;
typedef __attribute__((ext_vector_type(4))) float f32x4;

static __device__ __forceinline__ ushort f2bf(float f) {
    uint32_t u = __float_as_uint(f);
    uint32_t r = (u + 0x7fffu + ((u >> 16) & 1u)) >> 16;  // RNE
    return (ushort)r;
}
static __device__ __forceinline__ float bf2f(ushort b) {
    return __uint_as_float(((uint32_t)b) << 16);
}

// ---------------- CSR build ----------------

__global__ void deg_kernel(const int* __restrict__ dst, int* __restrict__ deg) {
    int e = blockIdx.x * blockDim.x + threadIdx.x;
    if (e < NEDGES) atomicAdd(&deg[dst[e]], 1);
}

// phase 1: per-block sums of deg; also compute dinv (fused)
__global__ __launch_bounds__(SCAN_BLK) void scan1_kernel(const int* __restrict__ deg,
                                                         int* __restrict__ blkSum,
                                                         float* __restrict__ dinv) {
    int i = blockIdx.x * SCAN_BLK + threadIdx.x;
    int d = (i < NNODES) ? deg[i] : 0;
    if (i < NNODES) dinv[i] = rsqrtf((float)d + 1.0f);
    int v = d;
#pragma unroll
    for (int off = 32; off; off >>= 1) v += __shfl_xor(v, off, 64);
    __shared__ int ws[SCAN_BLK / 64];
    int w = threadIdx.x >> 6;
    if ((threadIdx.x & 63) == 0) ws[w] = v;
    __syncthreads();
    if (threadIdx.x == 0) {
        int s = 0;
#pragma unroll
        for (int k = 0; k < SCAN_BLK / 64; ++k) s += ws[k];
        blkSum[blockIdx.x] = s;
    }
}

// phase 2: exclusive scan of the 98 block sums (single small block)
__global__ void scan2_kernel(int* __restrict__ blkSum, int* __restrict__ rowptr) {
    __shared__ int sh[128];
    int t = threadIdx.x;
    int v = (t < SCAN_NB) ? blkSum[t] : 0;
    sh[t] = v;
    __syncthreads();
    for (int off = 1; off < 128; off <<= 1) {
        int o = (t >= off) ? sh[t - off] : 0;
        __syncthreads();
        sh[t] += o;
        __syncthreads();
    }
    if (t < SCAN_NB) blkSum[t] = sh[t] - v;  // exclusive
    if (t == 0) rowptr[NNODES] = NEDGES;     // every edge has a dst
}

// phase 3: per-block exclusive scan + block offset -> rowptr
__global__ __launch_bounds__(SCAN_BLK) void scan3_kernel(const int* __restrict__ deg,
                                                         const int* __restrict__ blkOff,
                                                         int* __restrict__ rowptr) {
    int i = blockIdx.x * SCAN_BLK + threadIdx.x;
    int v = (i < NNODES) ? deg[i] : 0;
    int lane = threadIdx.x & 63;
    int w = threadIdx.x >> 6;
    int inc = v;
#pragma unroll
    for (int off = 1; off < 64; off <<= 1) {
        int o = __shfl_up(inc, off, 64);
        if (lane >= off) inc += o;
    }
    __shared__ int ws[SCAN_BLK / 64];
    if (lane == 63) ws[w] = inc;
    __syncthreads();
    int wpre = 0;
    for (int k = 0; k < w; ++k) wpre += ws[k];
    if (i < NNODES) rowptr[i] = inc - v + wpre + blkOff[blockIdx.x];
}

__global__ void scatter_kernel(const int* __restrict__ src, const int* __restrict__ dst,
                               const int* __restrict__ rowptr, int* __restrict__ cursor,
                               const float* __restrict__ dinv, int2* __restrict__ csr) {
    int e = blockIdx.x * blockDim.x + threadIdx.x;
    if (e >= NEDGES) return;
    int d = dst[e];
    int s = src[e];
    int pos = rowptr[d] + atomicAdd(&cursor[d], 1);
    csr[pos] = make_int2(s, __float_as_int(dinv[s]));
}

// ---------------- W pre-pack into MFMA B-fragment order (bf16) ----------------
template <int NOUT, int KS, int CF>
__global__ void pack_kernel(const float* __restrict__ W, ushort* __restrict__ pack) {
    int t = blockIdx.x * blockDim.x + threadIdx.x;
    if (t >= KS * CF * 64 * 8) return;
    int j = t & 7;
    int lane = (t >> 3) & 63;
    int cf = (t >> 9) % CF;
    int ks = t / (CF * 512);
    int k = ks * 32 + (lane >> 4) * 8 + j;
    int c = cf * 16 + (lane & 15);
    pack[t] = f2bf(W[(size_t)k * NOUT + c]);
}

// ---------------- GEMM1: xw1[50000x128](bf16) = x[50000x512](f32) @ packW1 ----------------
// 4-wave block, 64 rows, K-chunk 64. Double-buffered LDS A staging via global_load_lds
// (barrier-pipelined: compiler cannot sink the async stage past __syncthreads()).
// XOR swizzle (both sides): stored colb16 = logical colb16 ^ ((row&7)<<4); LDS dest stays
// linear, global SOURCE is pre-swizzled, ds_read applies the same XOR. Conflict-free b128.
__global__ __launch_bounds__(256) void gemm1_kernel(const float* __restrict__ A,
                                                    const ushort* __restrict__ packB,
                                                    ushort* __restrict__ C) {
    __shared__ float lds[2][64 * 64];  // 2 x 16 KB
    const int t = threadIdx.x;
    const int lane = t & 63;
    const int w = t >> 6;
    const int rowBase = blockIdx.x * 64;
    const int rl = lane & 15;
    const int kg = lane >> 4;

    // staging addressing
    const int Rloc = (w << 2) + (lane >> 4);            // row within chunk (+16 per round)
    const int csw = ((lane & 15) << 4) ^ ((Rloc & 7) << 4);  // swizzled source col-byte
    const char* Abase = (const char*)A;

    // compute-side addressing
    const int xr = (rl & 7) << 4;

    f32x4 acc[8];
#pragma unroll
    for (int cf = 0; cf < 8; ++cf) acc[cf] = (f32x4)(0.f);

    auto stage = [&](int buf, int chunk) {
#pragma unroll
        for (int r = 0; r < 4; ++r) {
            int row = rowBase + r * 16 + Rloc;
            if (row > NNODES - 1) row = NNODES - 1;  // clamp tail (data unused)
            const char* src = Abase + (size_t)row * (NIN * 4) + chunk * 256 + csw;
            char* dst = (char*)&lds[buf][0] + r * 4096 + w * 1024 + lane * 16;
            __builtin_amdgcn_global_load_lds((const uint32_t*)src, (uint32_t*)dst, 16, 0, 0);
        }
    };

    stage(0, 0);
    int buf = 0;
#pragma unroll
    for (int tch = 0; tch < 8; ++tch) {
        __syncthreads();  // drains vmcnt(0): buf is staged; buf^1 safe to overwrite
        if (tch + 1 < 8) stage(buf ^ 1, tch + 1);
        const char* lrow = (const char*)&lds[buf][0] + (w * 16 + rl) * 256;
#pragma unroll
        for (int ks = 0; ks < 2; ++ks) {
            float4 x0 = *(const float4*)(lrow + ((ks * 128 + kg * 32) ^ xr));
            float4 x1 = *(const float4*)(lrow + ((ks * 128 + kg * 32 + 16) ^ xr));
            bf16x8 af;
            af[0] = (short)f2bf(x0.x); af[1] = (short)f2bf(x0.y);
            af[2] = (short)f2bf(x0.z); af[3] = (short)f2bf(x0.w);
            af[4] = (short)f2bf(x1.x); af[5] = (short)f2bf(x1.y);
            af[6] = (short)f2bf(x1.z); af[7] = (short)f2bf(x1.w);
            const ushort* bpp = packB + ((size_t)(tch * 2 + ks) * 8) * 512 + (size_t)lane * 8;
#pragma unroll
            for (int cf = 0; cf < 8; ++cf) {
                bf16x8 bfv = *(const bf16x8*)(bpp + cf * 512);
                acc[cf] = __builtin_amdgcn_mfma_f32_16x16x32_bf16(af, bfv, acc[cf], 0, 0, 0);
            }
        }
        buf ^= 1;
    }
    // C/D: col = lane&15, row = (lane>>4)*4 + j   [m89-verified]
    const int rowW = rowBase + w * 16;
#pragma unroll
    for (int cf = 0; cf < 8; ++cf)
#pragma unroll
        for (int j = 0; j < 4; ++j) {
            int rr = rowW + kg * 4 + j;
            if (rr < NNODES) C[(size_t)rr * NHID + cf * 16 + rl] = f2bf(acc[cf][j]);
        }
}

// ---------------- GEMM2: xw2[50000x64](bf16) = h[50000x128](bf16) @ packW2 ----------------
__global__ __launch_bounds__(256) void gemm2_kernel(const ushort* __restrict__ A,
                                                    const ushort* __restrict__ packB,
                                                    ushort* __restrict__ C) {
    int wid = (blockIdx.x * blockDim.x + threadIdx.x) >> 6;
    int lane = threadIdx.x & 63;
    int rowBase = wid * 16;
    if (rowBase >= NNODES) return;
    int rl = lane & 15;
    int kg = lane >> 4;
    const ushort* ap = A + (size_t)(rowBase + rl) * NHID + kg * 8;

    f32x4 acc[4];
#pragma unroll
    for (int cf = 0; cf < 4; ++cf) acc[cf] = (f32x4)(0.f);

#pragma unroll
    for (int ks = 0; ks < 4; ++ks) {
        bf16x8 af = *(const bf16x8*)(ap + ks * 32);
        const ushort* bp = packB + ((size_t)(ks * 4) * 64 + lane) * 8;
#pragma unroll
        for (int cf = 0; cf < 4; ++cf) {
            bf16x8 bf = *(const bf16x8*)(bp + (size_t)cf * 512);
            acc[cf] = __builtin_amdgcn_mfma_f32_16x16x32_bf16(af, bf, acc[cf], 0, 0, 0);
        }
    }
#pragma unroll
    for (int cf = 0; cf < 4; ++cf)
#pragma unroll
        for (int j = 0; j < 4; ++j)
            C[(size_t)(rowBase + kg * 4 + j) * NCLS + cf * 16 + rl] = f2bf(acc[cf][j]);
}

// ---------------- agg1: h = relu(agg(xw1) + b1), one wave per node, bf16 in/out ----------------
__global__ __launch_bounds__(256) void agg1_kernel(const ushort* __restrict__ xw,
                                                   const int* __restrict__ rowptr,
                                                   const int2* __restrict__ csr,
                                                   const float* __restrict__ dinv,
                                                   const float* __restrict__ b1,
                                                   ushort* __restrict__ h) {
    int wid = (blockIdx.x * blockDim.x + threadIdx.x) >> 6;
    int lane = threadIdx.x & 63;
    if (wid >= NNODES) return;
    int beg = rowptr[wid], end = rowptr[wid + 1];
    float a0 = 0.f, a1 = 0.f;
    int j = beg;
    for (; j + 8 <= end; j += 8) {
        int2 e[8];
#pragma unroll
        for (int q = 0; q < 8; ++q) e[q] = csr[j + q];
        uint v[8];
#pragma unroll
        for (int q = 0; q < 8; ++q) v[q] = *(const uint*)&xw[(size_t)e[q].x * NHID + lane * 2];
#pragma unroll
        for (int q = 0; q < 8; ++q) {
            float wq = __int_as_float(e[q].y);
            a0 += wq * __uint_as_float(v[q] << 16);
            a1 += wq * __uint_as_float(v[q] & 0xffff0000u);
        }
    }
    for (; j < end; ++j) {
        int2 e = csr[j];
        float w = __int_as_float(e.y);
        uint v = *(const uint*)&xw[(size_t)e.x * NHID + lane * 2];
        a0 += w * __uint_as_float(v << 16);
        a1 += w * __uint_as_float(v & 0xffff0000u);
    }
    float di = dinv[wid];
    float sl = di * di;
    uint xv = *(const uint*)&xw[(size_t)wid * NHID + lane * 2];
    float2 bv = *(const float2*)&b1[lane * 2];
    float r0 = di * a0 + sl * __uint_as_float(xv << 16) + bv.x;
    float r1 = di * a1 + sl * __uint_as_float(xv & 0xffff0000u) + bv.y;
    uint o = (uint)f2bf(fmaxf(r0, 0.f)) | ((uint)f2bf(fmaxf(r1, 0.f)) << 16);
    *(uint*)&h[(size_t)wid * NHID + lane * 2] = o;
}

// ---------------- agg2 + bias + log_softmax, one wave per node, bf16 in, f32 out ----------------
__global__ __launch_bounds__(256) void agg2_kernel(const ushort* __restrict__ xw,
                                                   const int* __restrict__ rowptr,
                                                   const int2* __restrict__ csr,
                                                   const float* __restrict__ dinv,
                                                   const float* __restrict__ b2,
                                                   float* __restrict__ out) {
    int wid = (blockIdx.x * blockDim.x + threadIdx.x) >> 6;
    int lane = threadIdx.x & 63;
    if (wid >= NNODES) return;
    int beg = rowptr[wid], end = rowptr[wid + 1];
    float a = 0.f;
    int j = beg;
    for (; j + 8 <= end; j += 8) {
        int2 e[8];
#pragma unroll
        for (int q = 0; q < 8; ++q) e[q] = csr[j + q];
        float v[8];
#pragma unroll
        for (int q = 0; q < 8; ++q) v[q] = bf2f(xw[(size_t)e[q].x * NCLS + lane]);
#pragma unroll
        for (int q = 0; q < 8; ++q) a += __int_as_float(e[q].y) * v[q];
    }
    for (; j < end; ++j) {
        int2 e = csr[j];
        a += __int_as_float(e.y) * bf2f(xw[(size_t)e.x * NCLS + lane]);
    }
    float di = dinv[wid];
    float o = di * a + di * di * bf2f(xw[(size_t)wid * NCLS + lane]) + b2[lane];
    float m = o;
#pragma unroll
    for (int off = 32; off; off >>= 1) m = fmaxf(m, __shfl_xor(m, off, 64));
    float ex = __expf(o - m);
    float ssum = ex;
#pragma unroll
    for (int off = 32; off; off >>= 1) ssum += __shfl_xor(ssum, off, 64);
    out[(size_t)wid * NCLS + lane] = (o - m) - __logf(ssum);
}

// ---------------- launch ----------------

extern "C" void kernel_launch(void* const* d_in, const int* in_sizes, int n_in,
                              void* d_out, int out_size, void* d_ws, size_t ws_size,
                              hipStream_t stream) {
    const float* x  = (const float*)d_in[0];
    const int*   ei = (const int*)d_in[1];
    const int*   src = ei;
    const int*   dst = ei + NEDGES;
    const float* W1 = (const float*)d_in[2];
    const float* b1 = (const float*)d_in[3];
    const float* W2 = (const float*)d_in[4];
    const float* b2 = (const float*)d_in[5];
    float* out = (float*)d_out;

    char* w = (char*)d_ws;
    auto alloc = [&](size_t bytes) {
        char* p = w;
        w += (bytes + 255) & ~(size_t)255;
        return p;
    };
    int*    deg    = (int*)alloc((size_t)2 * NNODES * 4);  // deg + cursor (one memset)
    int*    cursor = deg + NNODES;
    int*    rowptr = (int*)alloc((NNODES + 1) * 4);
    int*    blkSum = (int*)alloc(SCAN_NB * 4);
    int2*   csr    = (int2*)alloc((size_t)NEDGES * 8);
    float*  dinv   = (float*)alloc(NNODES * 4);
    ushort* pack1  = (ushort*)alloc((size_t)16 * 8 * 64 * 8 * 2);
    ushort* pack2  = (ushort*)alloc((size_t)4 * 4 * 64 * 8 * 2);
    ushort* xw1    = (ushort*)alloc((size_t)NNODES * NHID * 2);
    ushort* h      = (ushort*)alloc((size_t)NNODES * NHID * 2);
    ushort* xw2    = (ushort*)alloc((size_t)NNODES * NCLS * 2);

    hipMemsetAsync(deg, 0, (size_t)2 * NNODES * 4, stream);

    deg_kernel<<<(NEDGES + 255) / 256, 256, 0, stream>>>(dst, deg);
    scan1_kernel<<<SCAN_NB, SCAN_BLK, 0, stream>>>(deg, blkSum, dinv);
    scan2_kernel<<<1, 128, 0, stream>>>(blkSum, rowptr);
    scan3_kernel<<<SCAN_NB, SCAN_BLK, 0, stream>>>(deg, blkSum, rowptr);
    scatter_kernel<<<(NEDGES + 255) / 256, 256, 0, stream>>>(src, dst, rowptr, cursor, dinv, csr);

    pack_kernel<NHID, 16, 8><<<(16 * 8 * 64 * 8 + 255) / 256, 256, 0, stream>>>(W1, pack1);
    pack_kernel<NCLS, 4, 4><<<(4 * 4 * 64 * 8 + 255) / 256, 256, 0, stream>>>(W2, pack2);

    // layer 1
    gemm1_kernel<<<(NNODES + 63) / 64, 256, 0, stream>>>(x, pack1, xw1);
    agg1_kernel<<<(NNODES * 64 + 255) / 256, 256, 0, stream>>>(xw1, rowptr, csr, dinv, b1, h);

    // layer 2 (+ fused bias + log_softmax)
    gemm2_kernel<<<(NNODES / 16 + 3) / 4, 256, 0, stream>>>(h, pack2, xw2);
    agg2_kernel<<<(NNODES * 64 + 255) / 256, 256, 0, stream>>>(xw2, rowptr, csr, dinv, b2, out);
}

// Round 7
// 209.471 us; speedup vs baseline: 2.3197x; 1.0153x over previous
//
#include <hip/hip_runtime.h>
#include <hip/hip_bf16.h>
#include <cstdint>
#include <cstddef>

#define NNODES 50000
#define NEDGES 800000
#define NIN    512
#define NHID   128
#define NCLS   64

#define SCAN_BLK 512
#define SCAN_NB ((NNODES + SCAN_BLK - 1) / SCAN_BLK)  // 98

typedef __attribute__((ext_vector_type(8))) short bf16x8;
typedef __attribute__((ext_vector_type(4))) float f32x4;

static __device__ __forceinline__ ushort f2bf(float f) {
    uint32_t u = __float_as_uint(f);
    uint32_t r = (u + 0x7fffu + ((u >> 16) & 1u)) >> 16;  // RNE
    return (ushort)r;
}
static __device__ __forceinline__ float bf2f(ushort b) {
    return __uint_as_float(((uint32_t)b) << 16);
}

// ---------------- workspace clear (hipMemsetAsync's fillBuffer = 58 us for 400 KB!) ----------------
__global__ void clear_kernel(int4* __restrict__ p, int n4) {
    int i = blockIdx.x * blockDim.x + threadIdx.x;
    if (i < n4) p[i] = make_int4(0, 0, 0, 0);
}

// ---------------- CSR build ----------------

__global__ void deg_kernel(const int* __restrict__ dst, int* __restrict__ deg) {
    int e = blockIdx.x * blockDim.x + threadIdx.x;
    if (e < NEDGES) atomicAdd(&deg[dst[e]], 1);
}

// phase 1: per-block sums of deg; also compute dinv (fused)
__global__ __launch_bounds__(SCAN_BLK) void scan1_kernel(const int* __restrict__ deg,
                                                         int* __restrict__ blkSum,
                                                         float* __restrict__ dinv) {
    int i = blockIdx.x * SCAN_BLK + threadIdx.x;
    int d = (i < NNODES) ? deg[i] : 0;
    if (i < NNODES) dinv[i] = rsqrtf((float)d + 1.0f);
    int v = d;
#pragma unroll
    for (int off = 32; off; off >>= 1) v += __shfl_xor(v, off, 64);
    __shared__ int ws[SCAN_BLK / 64];
    int w = threadIdx.x >> 6;
    if ((threadIdx.x & 63) == 0) ws[w] = v;
    __syncthreads();
    if (threadIdx.x == 0) {
        int s = 0;
#pragma unroll
        for (int k = 0; k < SCAN_BLK / 64; ++k) s += ws[k];
        blkSum[blockIdx.x] = s;
    }
}

// phase 2: exclusive scan of the 98 block sums (single small block)
__global__ void scan2_kernel(int* __restrict__ blkSum, int* __restrict__ rowptr) {
    __shared__ int sh[128];
    int t = threadIdx.x;
    int v = (t < SCAN_NB) ? blkSum[t] : 0;
    sh[t] = v;
    __syncthreads();
    for (int off = 1; off < 128; off <<= 1) {
        int o = (t >= off) ? sh[t - off] : 0;
        __syncthreads();
        sh[t] += o;
        __syncthreads();
    }
    if (t < SCAN_NB) blkSum[t] = sh[t] - v;  // exclusive
    if (t == 0) rowptr[NNODES] = NEDGES;     // every edge has a dst
}

// phase 3: per-block exclusive scan + block offset -> rowptr
__global__ __launch_bounds__(SCAN_BLK) void scan3_kernel(const int* __restrict__ deg,
                                                         const int* __restrict__ blkOff,
                                                         int* __restrict__ rowptr) {
    int i = blockIdx.x * SCAN_BLK + threadIdx.x;
    int v = (i < NNODES) ? deg[i] : 0;
    int lane = threadIdx.x & 63;
    int w = threadIdx.x >> 6;
    int inc = v;
#pragma unroll
    for (int off = 1; off < 64; off <<= 1) {
        int o = __shfl_up(inc, off, 64);
        if (lane >= off) inc += o;
    }
    __shared__ int ws[SCAN_BLK / 64];
    if (lane == 63) ws[w] = inc;
    __syncthreads();
    int wpre = 0;
    for (int k = 0; k < w; ++k) wpre += ws[k];
    if (i < NNODES) rowptr[i] = inc - v + wpre + blkOff[blockIdx.x];
}

__global__ void scatter_kernel(const int* __restrict__ src, const int* __restrict__ dst,
                               const int* __restrict__ rowptr, int* __restrict__ cursor,
                               const float* __restrict__ dinv, int2* __restrict__ csr) {
    int e = blockIdx.x * blockDim.x + threadIdx.x;
    if (e >= NEDGES) return;
    int d = dst[e];
    int s = src[e];
    int pos = rowptr[d] + atomicAdd(&cursor[d], 1);
    csr[pos] = make_int2(s, __float_as_int(dinv[s]));
}

// ---------------- W pre-pack into MFMA B-fragment order (bf16) ----------------
template <int NOUT, int KS, int CF>
__global__ void pack_kernel(const float* __restrict__ W, ushort* __restrict__ pack) {
    int t = blockIdx.x * blockDim.x + threadIdx.x;
    if (t >= KS * CF * 64 * 8) return;
    int j = t & 7;
    int lane = (t >> 3) & 63;
    int cf = (t >> 9) % CF;
    int ks = t / (CF * 512);
    int k = ks * 32 + (lane >> 4) * 8 + j;
    int c = cf * 16 + (lane & 15);
    pack[t] = f2bf(W[(size_t)k * NOUT + c]);
}

// ---------------- GEMM1: xw1[50000x128](bf16) = x[50000x512](f32) @ packW1 ----------------
// 4-wave block, 64 rows, K-chunk 64. Double-buffered LDS A staging via global_load_lds
// (barrier-pipelined). XOR swizzle both sides: linear LDS dest, pre-swizzled global source,
// swizzled ds_read. Conflict-free b128.
__global__ __launch_bounds__(256) void gemm1_kernel(const float* __restrict__ A,
                                                    const ushort* __restrict__ packB,
                                                    ushort* __restrict__ C) {
    __shared__ float lds[2][64 * 64];  // 2 x 16 KB
    const int t = threadIdx.x;
    const int lane = t & 63;
    const int w = t >> 6;
    const int rowBase = blockIdx.x * 64;
    const int rl = lane & 15;
    const int kg = lane >> 4;

    // staging addressing
    const int Rloc = (w << 2) + (lane >> 4);                 // row within chunk (+16 per round)
    const int csw = ((lane & 15) << 4) ^ ((Rloc & 7) << 4);  // swizzled source col-byte
    const char* Abase = (const char*)A;

    // compute-side addressing
    const int xr = (rl & 7) << 4;

    f32x4 acc[8];
#pragma unroll
    for (int cf = 0; cf < 8; ++cf) acc[cf] = (f32x4)(0.f);

    auto stage = [&](int buf, int chunk) {
#pragma unroll
        for (int r = 0; r < 4; ++r) {
            int row = rowBase + r * 16 + Rloc;
            if (row > NNODES - 1) row = NNODES - 1;  // clamp tail (data unused)
            const char* src = Abase + (size_t)row * (NIN * 4) + chunk * 256 + csw;
            char* dst = (char*)&lds[buf][0] + r * 4096 + w * 1024 + lane * 16;
            __builtin_amdgcn_global_load_lds((const uint32_t*)src, (uint32_t*)dst, 16, 0, 0);
        }
    };

    stage(0, 0);
    int buf = 0;
#pragma unroll
    for (int tch = 0; tch < 8; ++tch) {
        __syncthreads();  // drains vmcnt(0): buf is staged; buf^1 safe to overwrite
        if (tch + 1 < 8) stage(buf ^ 1, tch + 1);
        const char* lrow = (const char*)&lds[buf][0] + (w * 16 + rl) * 256;
#pragma unroll
        for (int ks = 0; ks < 2; ++ks) {
            float4 x0 = *(const float4*)(lrow + ((ks * 128 + kg * 32) ^ xr));
            float4 x1 = *(const float4*)(lrow + ((ks * 128 + kg * 32 + 16) ^ xr));
            bf16x8 af;
            af[0] = (short)f2bf(x0.x); af[1] = (short)f2bf(x0.y);
            af[2] = (short)f2bf(x0.z); af[3] = (short)f2bf(x0.w);
            af[4] = (short)f2bf(x1.x); af[5] = (short)f2bf(x1.y);
            af[6] = (short)f2bf(x1.z); af[7] = (short)f2bf(x1.w);
            const ushort* bpp = packB + ((size_t)(tch * 2 + ks) * 8) * 512 + (size_t)lane * 8;
#pragma unroll
            for (int cf = 0; cf < 8; ++cf) {
                bf16x8 bfv = *(const bf16x8*)(bpp + cf * 512);
                acc[cf] = __builtin_amdgcn_mfma_f32_16x16x32_bf16(af, bfv, acc[cf], 0, 0, 0);
            }
        }
        buf ^= 1;
    }
    // C/D: col = lane&15, row = (lane>>4)*4 + j   [m89-verified]
    const int rowW = rowBase + w * 16;
#pragma unroll
    for (int cf = 0; cf < 8; ++cf)
#pragma unroll
        for (int j = 0; j < 4; ++j) {
            int rr = rowW + kg * 4 + j;
            if (rr < NNODES) C[(size_t)rr * NHID + cf * 16 + rl] = f2bf(acc[cf][j]);
        }
}

// ---------------- GEMM2: xw2[50000x64](bf16) = h[50000x128](bf16) @ packW2 ----------------
__global__ __launch_bounds__(256) void gemm2_kernel(const ushort* __restrict__ A,
                                                    const ushort* __restrict__ packB,
                                                    ushort* __restrict__ C) {
    int wid = (blockIdx.x * blockDim.x + threadIdx.x) >> 6;
    int lane = threadIdx.x & 63;
    int rowBase = wid * 16;
    if (rowBase >= NNODES) return;
    int rl = lane & 15;
    int kg = lane >> 4;
    const ushort* ap = A + (size_t)(rowBase + rl) * NHID + kg * 8;

    f32x4 acc[4];
#pragma unroll
    for (int cf = 0; cf < 4; ++cf) acc[cf] = (f32x4)(0.f);

#pragma unroll
    for (int ks = 0; ks < 4; ++ks) {
        bf16x8 af = *(const bf16x8*)(ap + ks * 32);
        const ushort* bp = packB + ((size_t)(ks * 4) * 64 + lane) * 8;
#pragma unroll
        for (int cf = 0; cf < 4; ++cf) {
            bf16x8 bf = *(const bf16x8*)(bp + (size_t)cf * 512);
            acc[cf] = __builtin_amdgcn_mfma_f32_16x16x32_bf16(af, bf, acc[cf], 0, 0, 0);
        }
    }
#pragma unroll
    for (int cf = 0; cf < 4; ++cf)
#pragma unroll
        for (int j = 0; j < 4; ++j)
            C[(size_t)(rowBase + kg * 4 + j) * NCLS + cf * 16 + rl] = f2bf(acc[cf][j]);
}

// ---------------- agg1: h = relu(agg(xw1) + b1), one wave per node, bf16 in/out ----------------
__global__ __launch_bounds__(256) void agg1_kernel(const ushort* __restrict__ xw,
                                                   const int* __restrict__ rowptr,
                                                   const int2* __restrict__ csr,
                                                   const float* __restrict__ dinv,
                                                   const float* __restrict__ b1,
                                                   ushort* __restrict__ h) {
    int wid = (blockIdx.x * blockDim.x + threadIdx.x) >> 6;
    int lane = threadIdx.x & 63;
    if (wid >= NNODES) return;
    int beg = rowptr[wid], end = rowptr[wid + 1];
    float a0 = 0.f, a1 = 0.f;
    int j = beg;
    for (; j + 8 <= end; j += 8) {
        int2 e[8];
#pragma unroll
        for (int q = 0; q < 8; ++q) e[q] = csr[j + q];
        uint v[8];
#pragma unroll
        for (int q = 0; q < 8; ++q) v[q] = *(const uint*)&xw[(size_t)e[q].x * NHID + lane * 2];
#pragma unroll
        for (int q = 0; q < 8; ++q) {
            float wq = __int_as_float(e[q].y);
            a0 += wq * __uint_as_float(v[q] << 16);
            a1 += wq * __uint_as_float(v[q] & 0xffff0000u);
        }
    }
    for (; j < end; ++j) {
        int2 e = csr[j];
        float w = __int_as_float(e.y);
        uint v = *(const uint*)&xw[(size_t)e.x * NHID + lane * 2];
        a0 += w * __uint_as_float(v << 16);
        a1 += w * __uint_as_float(v & 0xffff0000u);
    }
    float di = dinv[wid];
    float sl = di * di;
    uint xv = *(const uint*)&xw[(size_t)wid * NHID + lane * 2];
    float2 bv = *(const float2*)&b1[lane * 2];
    float r0 = di * a0 + sl * __uint_as_float(xv << 16) + bv.x;
    float r1 = di * a1 + sl * __uint_as_float(xv & 0xffff0000u) + bv.y;
    uint o = (uint)f2bf(fmaxf(r0, 0.f)) | ((uint)f2bf(fmaxf(r1, 0.f)) << 16);
    *(uint*)&h[(size_t)wid * NHID + lane * 2] = o;
}

// ---------------- agg2 + bias + log_softmax, one wave per node, bf16 in, f32 out ----------------
__global__ __launch_bounds__(256) void agg2_kernel(const ushort* __restrict__ xw,
                                                   const int* __restrict__ rowptr,
                                                   const int2* __restrict__ csr,
                                                   const float* __restrict__ dinv,
                                                   const float* __restrict__ b2,
                                                   float* __restrict__ out) {
    int wid = (blockIdx.x * blockDim.x + threadIdx.x) >> 6;
    int lane = threadIdx.x & 63;
    if (wid >= NNODES) return;
    int beg = rowptr[wid], end = rowptr[wid + 1];
    float a = 0.f;
    int j = beg;
    for (; j + 8 <= end; j += 8) {
        int2 e[8];
#pragma unroll
        for (int q = 0; q < 8; ++q) e[q] = csr[j + q];
        float v[8];
#pragma unroll
        for (int q = 0; q < 8; ++q) v[q] = bf2f(xw[(size_t)e[q].x * NCLS + lane]);
#pragma unroll
        for (int q = 0; q < 8; ++q) a += __int_as_float(e[q].y) * v[q];
    }
    for (; j < end; ++j) {
        int2 e = csr[j];
        a += __int_as_float(e.y) * bf2f(xw[(size_t)e.x * NCLS + lane]);
    }
    float di = dinv[wid];
    float o = di * a + di * di * bf2f(xw[(size_t)wid * NCLS + lane]) + b2[lane];
    float m = o;
#pragma unroll
    for (int off = 32; off; off >>= 1) m = fmaxf(m, __shfl_xor(m, off, 64));
    float ex = __expf(o - m);
    float ssum = ex;
#pragma unroll
    for (int off = 32; off; off >>= 1) ssum += __shfl_xor(ssum, off, 64);
    out[(size_t)wid * NCLS + lane] = (o - m) - __logf(ssum);
}

// ---------------- launch ----------------

extern "C" void kernel_launch(void* const* d_in, const int* in_sizes, int n_in,
                              void* d_out, int out_size, void* d_ws, size_t ws_size,
                              hipStream_t stream) {
    const float* x  = (const float*)d_in[0];
    const int*   ei = (const int*)d_in[1];
    const int*   src = ei;
    const int*   dst = ei + NEDGES;
    const float* W1 = (const float*)d_in[2];
    const float* b1 = (const float*)d_in[3];
    const float* W2 = (const float*)d_in[4];
    const float* b2 = (const float*)d_in[5];
    float* out = (float*)d_out;

    char* w = (char*)d_ws;
    auto alloc = [&](size_t bytes) {
        char* p = w;
        w += (bytes + 255) & ~(size_t)255;
        return p;
    };
    int*    deg    = (int*)alloc((size_t)2 * NNODES * 4);  // deg + cursor (one clear)
    int*    cursor = deg + NNODES;
    int*    rowptr = (int*)alloc((NNODES + 1) * 4);
    int*    blkSum = (int*)alloc(SCAN_NB * 4);
    int2*   csr    = (int2*)alloc((size_t)NEDGES * 8);
    float*  dinv   = (float*)alloc(NNODES * 4);
    ushort* pack1  = (ushort*)alloc((size_t)16 * 8 * 64 * 8 * 2);
    ushort* pack2  = (ushort*)alloc((size_t)4 * 4 * 64 * 8 * 2);
    ushort* xw1    = (ushort*)alloc((size_t)NNODES * NHID * 2);
    ushort* h      = (ushort*)alloc((size_t)NNODES * NHID * 2);
    ushort* xw2    = (ushort*)alloc((size_t)NNODES * NCLS * 2);

    // custom clear: rocclr fillBuffer costs 58 us for 400 KB (latency-bound tiny grid)
    const int n4 = (2 * NNODES + 3) / 4;  // deg+cursor as int4
    clear_kernel<<<(n4 + 255) / 256, 256, 0, stream>>>((int4*)deg, n4);

    deg_kernel<<<(NEDGES + 255) / 256, 256, 0, stream>>>(dst, deg);
    scan1_kernel<<<SCAN_NB, SCAN_BLK, 0, stream>>>(deg, blkSum, dinv);
    scan2_kernel<<<1, 128, 0, stream>>>(blkSum, rowptr);
    scan3_kernel<<<SCAN_NB, SCAN_BLK, 0, stream>>>(deg, blkSum, rowptr);
    scatter_kernel<<<(NEDGES + 255) / 256, 256, 0, stream>>>(src, dst, rowptr, cursor, dinv, csr);

    pack_kernel<NHID, 16, 8><<<(16 * 8 * 64 * 8 + 255) / 256, 256, 0, stream>>>(W1, pack1);
    pack_kernel<NCLS, 4, 4><<<(4 * 4 * 64 * 8 + 255) / 256, 256, 0, stream>>>(W2, pack2);

    // layer 1
    gemm1_kernel<<<(NNODES + 63) / 64, 256, 0, stream>>>(x, pack1, xw1);
    agg1_kernel<<<(NNODES * 64 + 255) / 256, 256, 0, stream>>>(xw1, rowptr, csr, dinv, b1, h);

    // layer 2 (+ fused bias + log_softmax)
    gemm2_kernel<<<(NNODES / 16 + 3) / 4, 256, 0, stream>>>(h, pack2, xw2);
    agg2_kernel<<<(NNODES * 64 + 255) / 256, 256, 0, stream>>>(xw2, rowptr, csr, dinv, b2, out);
}